// Round 2
// baseline (386.494 us; speedup 1.0000x reference)
//
#include <hip/hip_runtime.h>

#define OUT 7
#define CCH 256

__device__ __forceinline__ unsigned short f2bf(float f) {
    union { float f; unsigned int u; } v; v.f = f;
    unsigned int r = (v.u + 0x7FFFu + ((v.u >> 16) & 1u)) >> 16;   // RNE
    return (unsigned short)r;
}
__device__ __forceinline__ float bf2f(unsigned short h) {
    union { unsigned int u; float f; } v; v.u = ((unsigned int)h) << 16;
    return v.f;
}

// ---------------- fallback: one thread per output elem (no ws needed) ------
__global__ __launch_bounds__(256) void roi_pool_naive(
    const float* __restrict__ f0, const float* __restrict__ f1,
    const float* __restrict__ f2, const float* __restrict__ f3,
    const float* __restrict__ boxes, float* __restrict__ out,
    int M, int R)
{
    int idx = blockIdx.x * blockDim.x + threadIdx.x;
    int total = M * CCH * OUT * OUT;
    if (idx >= total) return;
    int pw = idx % OUT;
    int ph = (idx / OUT) % OUT;
    int c  = (idx / (OUT * OUT)) % CCH;
    int m  = idx / (OUT * OUT * CCH);
    int n  = m / R;
    const float bx1 = boxes[m * 4 + 0], by1 = boxes[m * 4 + 1];
    const float bx2 = boxes[m * 4 + 2], by2 = boxes[m * 4 + 3];
    float sz  = sqrtf(fmaxf((bx2 - bx1) * (by2 - by1), 0.0f));
    int lvl = (int)floorf(4.0f + log2f(sz / 224.0f + 1e-8f));
    lvl = min(max(lvl, 2), 5) - 2;
    const float* feat; int H, W; float scale;
    switch (lvl) {
        case 0:  feat = f0; H = 256; W = 256; scale = 0.25f;    break;
        case 1:  feat = f1; H = 128; W = 128; scale = 0.125f;   break;
        case 2:  feat = f2; H = 64;  W = 64;  scale = 0.0625f;  break;
        default: feat = f3; H = 32;  W = 32;  scale = 0.03125f; break;
    }
    const float* fp = feat + (size_t)(n * CCH + c) * (size_t)(H * W);
    float x1 = bx1 * scale - 0.5f, y1 = by1 * scale - 0.5f;
    float x2 = bx2 * scale - 0.5f, y2 = by2 * scale - 0.5f;
    float bw = (x2 - x1) * (1.0f / OUT), bh = (y2 - y1) * (1.0f / OUT);
    float acc = 0.0f;
    #pragma unroll
    for (int iy = 0; iy < 2; iy++) {
        float ys = y1 + ((float)ph + ((float)iy + 0.5f) * 0.5f) * bh;
        bool vy = (ys >= -1.0f) && (ys <= (float)H);
        float y = fminf(fmaxf(ys, 0.0f), (float)(H - 1));
        int y0 = (int)y;
        int y1i = min(y0 + 1, H - 1);
        float ly = y - (float)y0, hy = 1.0f - ly;
        #pragma unroll
        for (int ix = 0; ix < 2; ix++) {
            float xs = x1 + ((float)pw + ((float)ix + 0.5f) * 0.5f) * bw;
            bool vx = (xs >= -1.0f) && (xs <= (float)W);
            float x = fminf(fmaxf(xs, 0.0f), (float)(W - 1));
            int x0 = (int)x;
            int x1ii = min(x0 + 1, W - 1);
            float lx = x - (float)x0, hx = 1.0f - lx;
            if (vy && vx) {
                acc += hy * hx * fp[y0 * W + x0]  + hy * lx * fp[y0 * W + x1ii]
                     + ly * hx * fp[y1i * W + x0] + ly * lx * fp[y1i * W + x1ii];
            }
        }
    }
    out[idx] = acc * 0.25f;
}

// ---- fused NCHW fp32 -> NHWC bf16 transpose, all 4 levels, one launch -----
// linear grid; per level: (HW/64) hw-tiles x 4 c-tiles x N images.
__global__ __launch_bounds__(256) void transpose_all(
    const float* __restrict__ f0, const float* __restrict__ f1,
    const float* __restrict__ f2, const float* __restrict__ f3,
    unsigned short* __restrict__ o0, unsigned short* __restrict__ o1,
    unsigned short* __restrict__ o2, unsigned short* __restrict__ o3,
    int N)
{
    __shared__ float tile[64][65];   // [c_local][hw_local]; 2-way alias = free

    int rem = blockIdx.x;
    const int nb0 = 4096 * N;   // 1024 hw-tiles * 4 c-tiles * N
    const int nb1 = 1024 * N;
    const int nb2 = 256 * N;
    const float* in; unsigned short* op; int HW, lshift;
    if (rem < nb0)        { in = f0; op = o0; HW = 65536; lshift = 10; }
    else { rem -= nb0;
      if (rem < nb1)      { in = f1; op = o1; HW = 16384; lshift = 8;  }
      else { rem -= nb1;
        if (rem < nb2)    { in = f2; op = o2; HW = 4096;  lshift = 6;  }
        else { rem -= nb2;  in = f3; op = o3; HW = 1024;  lshift = 4;  }
      }
    }
    int hw0 = (rem & ((1 << lshift) - 1)) << 6;
    int c0  = ((rem >> lshift) & 3) << 6;
    int n   = rem >> (lshift + 2);

    int tid = threadIdx.x;
    int tx = tid & 15;    // 0..15
    int ty = tid >> 4;    // 0..15

    const float4* in4 = (const float4*)(in + (size_t)n * CCH * HW);
    #pragma unroll
    for (int j = 0; j < 4; j++) {
        int c = c0 + ty + 16 * j;
        float4 v = in4[((size_t)c * HW + hw0) / 4 + tx];
        tile[ty + 16 * j][4 * tx + 0] = v.x;
        tile[ty + 16 * j][4 * tx + 1] = v.y;
        tile[ty + 16 * j][4 * tx + 2] = v.z;
        tile[ty + 16 * j][4 * tx + 3] = v.w;
    }
    __syncthreads();
    unsigned short* ob = op + (size_t)n * HW * CCH;
    #pragma unroll
    for (int j = 0; j < 4; j++) {
        int hw = hw0 + ty + 16 * j;
        ushort4 u;
        u.x = f2bf(tile[4 * tx + 0][ty + 16 * j]);
        u.y = f2bf(tile[4 * tx + 1][ty + 16 * j]);
        u.z = f2bf(tile[4 * tx + 2][ty + 16 * j]);
        u.w = f2bf(tile[4 * tx + 3][ty + 16 * j]);
        ((ushort4*)(ob + (size_t)hw * CCH + c0))[tx] = u;
    }
}

// ---- main: one block per BOX; thread = channel; ph loop inside -------------
// Rows sampled by adjacent ph (and iy=0/1) overlap heavily -> with the whole
// box in one block those row segments stay L1-resident; box setup amortized 7x.
__global__ __launch_bounds__(256) void roi_pool_box(
    const unsigned short* __restrict__ t0, const unsigned short* __restrict__ t1,
    const unsigned short* __restrict__ t2, const unsigned short* __restrict__ t3,
    const float* __restrict__ boxes, float* __restrict__ out, int M, int R)
{
    int m = blockIdx.x;
    int t = threadIdx.x;          // channel
    int n = m / R;

    const float bx1 = boxes[m * 4 + 0], by1 = boxes[m * 4 + 1];
    const float bx2 = boxes[m * 4 + 2], by2 = boxes[m * 4 + 3];
    float sz  = sqrtf(fmaxf((bx2 - bx1) * (by2 - by1), 0.0f));
    int lvl = (int)floorf(4.0f + log2f(sz / 224.0f + 1e-8f));
    lvl = min(max(lvl, 2), 5) - 2;

    const unsigned short* feat; int H, W; float scale;
    switch (lvl) {
        case 0:  feat = t0; H = 256; W = 256; scale = 0.25f;    break;
        case 1:  feat = t1; H = 128; W = 128; scale = 0.125f;   break;
        case 2:  feat = t2; H = 64;  W = 64;  scale = 0.0625f;  break;
        default: feat = t3; H = 32;  W = 32;  scale = 0.03125f; break;
    }
    const unsigned short* fb = feat + (size_t)n * H * W * CCH;

    float x1 = bx1 * scale - 0.5f, y1 = by1 * scale - 0.5f;
    float x2 = bx2 * scale - 0.5f, y2 = by2 * scale - 0.5f;
    float bw = (x2 - x1) * (1.0f / OUT), bh = (y2 - y1) * (1.0f / OUT);

    float* obase = out + (size_t)m * (CCH * OUT * OUT) + (size_t)t * (OUT * OUT);

    for (int ph = 0; ph < OUT; ph++) {
        // two y-samples for this bin row (block-uniform)
        int   r0[2], r1[2];
        float lyv[2], hyv[2];
        bool  vyv[2];
        #pragma unroll
        for (int iy = 0; iy < 2; iy++) {
            float ys = y1 + ((float)ph + ((float)iy + 0.5f) * 0.5f) * bh;
            vyv[iy] = (ys >= -1.0f) && (ys <= (float)H);
            float y = fminf(fmaxf(ys, 0.0f), (float)(H - 1));
            int y0 = (int)y;
            int y1i = min(y0 + 1, H - 1);
            lyv[iy] = y - (float)y0;
            hyv[iy] = 1.0f - lyv[iy];
            r0[iy] = y0 * W * CCH;
            r1[iy] = y1i * W * CCH;
        }

        float acc[OUT];
        #pragma unroll
        for (int pw = 0; pw < OUT; pw++) {
            float a = 0.0f;
            #pragma unroll
            for (int ix = 0; ix < 2; ix++) {
                float xs = x1 + ((float)pw + ((float)ix + 0.5f) * 0.5f) * bw;
                bool vx = (xs >= -1.0f) && (xs <= (float)W);
                float x = fminf(fmaxf(xs, 0.0f), (float)(W - 1));
                int x0 = (int)x;
                int x1i = min(x0 + 1, W - 1);
                float lx = x - (float)x0;
                float hx = 1.0f - lx;
                int c0o = x0 * CCH;
                int c1o = x1i * CCH;
                #pragma unroll
                for (int iy = 0; iy < 2; iy++) {
                    if (vyv[iy] && vx) {
                        const unsigned short* p00 = fb + __builtin_amdgcn_readfirstlane(r0[iy] + c0o);
                        const unsigned short* p01 = fb + __builtin_amdgcn_readfirstlane(r0[iy] + c1o);
                        const unsigned short* p10 = fb + __builtin_amdgcn_readfirstlane(r1[iy] + c0o);
                        const unsigned short* p11 = fb + __builtin_amdgcn_readfirstlane(r1[iy] + c1o);
                        float v00 = bf2f(p00[t]), v01 = bf2f(p01[t]);
                        float v10 = bf2f(p10[t]), v11 = bf2f(p11[t]);
                        a += hyv[iy] * (hx * v00 + lx * v01)
                           + lyv[iy] * (hx * v10 + lx * v11);
                    }
                }
            }
            acc[pw] = a * 0.25f;
        }

        // thread t owns channel t's 7 values for this ph row: contiguous 28 B
        float* ob = obase + ph * OUT;
        #pragma unroll
        for (int k = 0; k < OUT; k++) ob[k] = acc[k];
    }
}

extern "C" void kernel_launch(void* const* d_in, const int* in_sizes, int n_in,
                              void* d_out, int out_size, void* d_ws, size_t ws_size,
                              hipStream_t stream) {
    const float* f0    = (const float*)d_in[0];
    const float* f1    = (const float*)d_in[1];
    const float* f2    = (const float*)d_in[2];
    const float* f3    = (const float*)d_in[3];
    const float* boxes = (const float*)d_in[4];
    float* out = (float*)d_out;

    int N = in_sizes[0] / (CCH * 256 * 256);
    int M = in_sizes[4] / 4;
    int R = M / N;

    size_t nshorts = (size_t)N * CCH * (65536 + 16384 + 4096 + 1024);
    if (ws_size >= nshorts * sizeof(unsigned short)) {
        unsigned short* t0 = (unsigned short*)d_ws;
        unsigned short* t1 = t0 + (size_t)N * CCH * 65536;
        unsigned short* t2 = t1 + (size_t)N * CCH * 16384;
        unsigned short* t3 = t2 + (size_t)N * CCH * 4096;
        int tblocks = (4096 + 1024 + 256 + 64) * N;   // 5440*N
        transpose_all<<<tblocks, 256, 0, stream>>>(f0, f1, f2, f3, t0, t1, t2, t3, N);
        roi_pool_box<<<M, 256, 0, stream>>>(t0, t1, t2, t3, boxes, out, M, R);
    } else {
        int total = M * CCH * OUT * OUT;
        roi_pool_naive<<<(total + 255) / 256, 256, 0, stream>>>(f0, f1, f2, f3, boxes, out, M, R);
    }
}

// Round 3
// 296.565 us; speedup vs baseline: 1.3032x; 1.3032x over previous
//
#include <hip/hip_runtime.h>

#define OUT 7
#define CCH 256

__device__ __forceinline__ unsigned short f2bf(float f) {
    union { float f; unsigned int u; } v; v.f = f;
    unsigned int r = (v.u + 0x7FFFu + ((v.u >> 16) & 1u)) >> 16;   // RNE
    return (unsigned short)r;
}
__device__ __forceinline__ float bf2f(unsigned short h) {
    union { unsigned int u; float f; } v; v.u = ((unsigned int)h) << 16;
    return v.f;
}
__device__ __forceinline__ float bf2f_lo(unsigned int u) {
    union { unsigned int u; float f; } v; v.u = u << 16;
    return v.f;
}
__device__ __forceinline__ float bf2f_hi(unsigned int u) {
    union { unsigned int u; float f; } v; v.u = u & 0xFFFF0000u;
    return v.f;
}

// ---------------- fallback: one thread per output elem (no ws needed) ------
__global__ __launch_bounds__(256) void roi_pool_naive(
    const float* __restrict__ f0, const float* __restrict__ f1,
    const float* __restrict__ f2, const float* __restrict__ f3,
    const float* __restrict__ boxes, float* __restrict__ out,
    int M, int R)
{
    int idx = blockIdx.x * blockDim.x + threadIdx.x;
    int total = M * CCH * OUT * OUT;
    if (idx >= total) return;
    int pw = idx % OUT;
    int ph = (idx / OUT) % OUT;
    int c  = (idx / (OUT * OUT)) % CCH;
    int m  = idx / (OUT * OUT * CCH);
    int n  = m / R;
    const float bx1 = boxes[m * 4 + 0], by1 = boxes[m * 4 + 1];
    const float bx2 = boxes[m * 4 + 2], by2 = boxes[m * 4 + 3];
    float sz  = sqrtf(fmaxf((bx2 - bx1) * (by2 - by1), 0.0f));
    int lvl = (int)floorf(4.0f + log2f(sz / 224.0f + 1e-8f));
    lvl = min(max(lvl, 2), 5) - 2;
    const float* feat; int H, W; float scale;
    switch (lvl) {
        case 0:  feat = f0; H = 256; W = 256; scale = 0.25f;    break;
        case 1:  feat = f1; H = 128; W = 128; scale = 0.125f;   break;
        case 2:  feat = f2; H = 64;  W = 64;  scale = 0.0625f;  break;
        default: feat = f3; H = 32;  W = 32;  scale = 0.03125f; break;
    }
    const float* fp = feat + (size_t)(n * CCH + c) * (size_t)(H * W);
    float x1 = bx1 * scale - 0.5f, y1 = by1 * scale - 0.5f;
    float x2 = bx2 * scale - 0.5f, y2 = by2 * scale - 0.5f;
    float bw = (x2 - x1) * (1.0f / OUT), bh = (y2 - y1) * (1.0f / OUT);
    float acc = 0.0f;
    #pragma unroll
    for (int iy = 0; iy < 2; iy++) {
        float ys = y1 + ((float)ph + ((float)iy + 0.5f) * 0.5f) * bh;
        bool vy = (ys >= -1.0f) && (ys <= (float)H);
        float y = fminf(fmaxf(ys, 0.0f), (float)(H - 1));
        int y0 = (int)y;
        int y1i = min(y0 + 1, H - 1);
        float ly = y - (float)y0, hy = 1.0f - ly;
        #pragma unroll
        for (int ix = 0; ix < 2; ix++) {
            float xs = x1 + ((float)pw + ((float)ix + 0.5f) * 0.5f) * bw;
            bool vx = (xs >= -1.0f) && (xs <= (float)W);
            float x = fminf(fmaxf(xs, 0.0f), (float)(W - 1));
            int x0 = (int)x;
            int x1ii = min(x0 + 1, W - 1);
            float lx = x - (float)x0, hx = 1.0f - lx;
            if (vy && vx) {
                acc += hy * hx * fp[y0 * W + x0]  + hy * lx * fp[y0 * W + x1ii]
                     + ly * hx * fp[y1i * W + x0] + ly * lx * fp[y1i * W + x1ii];
            }
        }
    }
    out[idx] = acc * 0.25f;
}

// ---- fused NCHW fp32 -> NHWC bf16 transpose, all 4 levels, one launch -----
__global__ __launch_bounds__(256) void transpose_all(
    const float* __restrict__ f0, const float* __restrict__ f1,
    const float* __restrict__ f2, const float* __restrict__ f3,
    unsigned short* __restrict__ o0, unsigned short* __restrict__ o1,
    unsigned short* __restrict__ o2, unsigned short* __restrict__ o3,
    int N)
{
    __shared__ float tile[64][65];   // [c_local][hw_local]; 2-way alias = free

    int rem = blockIdx.x;
    const int nb0 = 4096 * N;   // 1024 hw-tiles * 4 c-tiles * N
    const int nb1 = 1024 * N;
    const int nb2 = 256 * N;
    const float* in; unsigned short* op; int HW, lshift;
    if (rem < nb0)        { in = f0; op = o0; HW = 65536; lshift = 10; }
    else { rem -= nb0;
      if (rem < nb1)      { in = f1; op = o1; HW = 16384; lshift = 8;  }
      else { rem -= nb1;
        if (rem < nb2)    { in = f2; op = o2; HW = 4096;  lshift = 6;  }
        else { rem -= nb2;  in = f3; op = o3; HW = 1024;  lshift = 4;  }
      }
    }
    int hw0 = (rem & ((1 << lshift) - 1)) << 6;
    int c0  = ((rem >> lshift) & 3) << 6;
    int n   = rem >> (lshift + 2);

    int tid = threadIdx.x;
    int tx = tid & 15;    // 0..15
    int ty = tid >> 4;    // 0..15

    const float4* in4 = (const float4*)(in + (size_t)n * CCH * HW);
    #pragma unroll
    for (int j = 0; j < 4; j++) {
        int c = c0 + ty + 16 * j;
        float4 v = in4[((size_t)c * HW + hw0) / 4 + tx];
        tile[ty + 16 * j][4 * tx + 0] = v.x;
        tile[ty + 16 * j][4 * tx + 1] = v.y;
        tile[ty + 16 * j][4 * tx + 2] = v.z;
        tile[ty + 16 * j][4 * tx + 3] = v.w;
    }
    __syncthreads();
    unsigned short* ob = op + (size_t)n * HW * CCH;
    #pragma unroll
    for (int j = 0; j < 4; j++) {
        int hw = hw0 + ty + 16 * j;
        ushort4 u;
        u.x = f2bf(tile[4 * tx + 0][ty + 16 * j]);
        u.y = f2bf(tile[4 * tx + 1][ty + 16 * j]);
        u.z = f2bf(tile[4 * tx + 2][ty + 16 * j]);
        u.w = f2bf(tile[4 * tx + 3][ty + 16 * j]);
        ((ushort4*)(ob + (size_t)hw * CCH + c0))[tx] = u;
    }
}

// ---- main: one block per (box, ph); 128 threads; lane = 2 channels (uint) --
// Restores the round-0 parallelism (7168 blocks) that round-2 showed is the
// carrying factor (1024-block version: 139us, latency-bound at 33% occ).
// Change vs round-0: each lane loads a uint = 2 adjacent bf16 channels
// (256 B per wave-instruction instead of 128 B) -> total load instructions
// halve (3.2M -> 1.6M) at unchanged per-wave ILP.
__global__ __launch_bounds__(128) void roi_pool_cl2(
    const unsigned short* __restrict__ t0, const unsigned short* __restrict__ t1,
    const unsigned short* __restrict__ t2, const unsigned short* __restrict__ t3,
    const float* __restrict__ boxes, float* __restrict__ out, int M, int R)
{
    int bx = blockIdx.x;
    int m, ph;
    if ((M & 7) == 0) {
        // XCD swizzle: 56-block group = 8 boxes x 7 ph (see round-0 comment)
        int q = bx / 56, rem = bx - q * 56;
        ph = rem >> 3;
        m  = q * 8 + (rem & 7);
    } else {
        m = bx / OUT; ph = bx % OUT;
    }
    int t = threadIdx.x;          // channel-pair index: channels 2t, 2t+1
    int n = m / R;

    const float bx1 = boxes[m * 4 + 0], by1 = boxes[m * 4 + 1];
    const float bx2 = boxes[m * 4 + 2], by2 = boxes[m * 4 + 3];
    float sz  = sqrtf(fmaxf((bx2 - bx1) * (by2 - by1), 0.0f));
    int lvl = (int)floorf(4.0f + log2f(sz / 224.0f + 1e-8f));
    lvl = min(max(lvl, 2), 5) - 2;

    const unsigned short* feat; int H, W; float scale;
    switch (lvl) {
        case 0:  feat = t0; H = 256; W = 256; scale = 0.25f;    break;
        case 1:  feat = t1; H = 128; W = 128; scale = 0.125f;   break;
        case 2:  feat = t2; H = 64;  W = 64;  scale = 0.0625f;  break;
        default: feat = t3; H = 32;  W = 32;  scale = 0.03125f; break;
    }
    const unsigned short* fb = feat + (size_t)n * H * W * CCH;

    float x1 = bx1 * scale - 0.5f, y1 = by1 * scale - 0.5f;
    float x2 = bx2 * scale - 0.5f, y2 = by2 * scale - 0.5f;
    float bw = (x2 - x1) * (1.0f / OUT), bh = (y2 - y1) * (1.0f / OUT);

    // two y-samples for this bin row (block-uniform)
    int   r0[2], r1[2];
    float lyv[2], hyv[2];
    bool  vyv[2];
    #pragma unroll
    for (int iy = 0; iy < 2; iy++) {
        float ys = y1 + ((float)ph + ((float)iy + 0.5f) * 0.5f) * bh;
        vyv[iy] = (ys >= -1.0f) && (ys <= (float)H);
        float y = fminf(fmaxf(ys, 0.0f), (float)(H - 1));
        int y0 = (int)y;
        int y1i = min(y0 + 1, H - 1);
        lyv[iy] = y - (float)y0;
        hyv[iy] = 1.0f - lyv[iy];
        r0[iy] = y0 * W * CCH;
        r1[iy] = y1i * W * CCH;
    }

    float accA[OUT];   // channel 2t
    float accB[OUT];   // channel 2t+1
    #pragma unroll
    for (int pw = 0; pw < OUT; pw++) {
        float aA = 0.0f, aB = 0.0f;
        #pragma unroll
        for (int ix = 0; ix < 2; ix++) {
            float xs = x1 + ((float)pw + ((float)ix + 0.5f) * 0.5f) * bw;
            bool vx = (xs >= -1.0f) && (xs <= (float)W);
            float x = fminf(fmaxf(xs, 0.0f), (float)(W - 1));
            int x0 = (int)x;
            int x1i = min(x0 + 1, W - 1);
            float lx = x - (float)x0;
            float hx = 1.0f - lx;
            int c0o = x0 * CCH;
            int c1o = x1i * CCH;
            #pragma unroll
            for (int iy = 0; iy < 2; iy++) {
                if (vyv[iy] && vx) {
                    const unsigned int* p00 = (const unsigned int*)(fb + __builtin_amdgcn_readfirstlane(r0[iy] + c0o));
                    const unsigned int* p01 = (const unsigned int*)(fb + __builtin_amdgcn_readfirstlane(r0[iy] + c1o));
                    const unsigned int* p10 = (const unsigned int*)(fb + __builtin_amdgcn_readfirstlane(r1[iy] + c0o));
                    const unsigned int* p11 = (const unsigned int*)(fb + __builtin_amdgcn_readfirstlane(r1[iy] + c1o));
                    unsigned int u00 = p00[t], u01 = p01[t];
                    unsigned int u10 = p10[t], u11 = p11[t];
                    float w00 = hyv[iy] * hx, w01 = hyv[iy] * lx;
                    float w10 = lyv[iy] * hx, w11 = lyv[iy] * lx;
                    aA += w00 * bf2f_lo(u00) + w01 * bf2f_lo(u01)
                        + w10 * bf2f_lo(u10) + w11 * bf2f_lo(u11);
                    aB += w00 * bf2f_hi(u00) + w01 * bf2f_hi(u01)
                        + w10 * bf2f_hi(u10) + w11 * bf2f_hi(u11);
                }
            }
        }
        accA[pw] = aA * 0.25f;
        accB[pw] = aB * 0.25f;
    }

    // thread t owns channels 2t, 2t+1: two contiguous 28 B chunks
    float* obA = out + (size_t)m * (CCH * OUT * OUT) + (size_t)(2 * t) * (OUT * OUT) + ph * OUT;
    float* obB = obA + (OUT * OUT);
    #pragma unroll
    for (int k = 0; k < OUT; k++) obA[k] = accA[k];
    #pragma unroll
    for (int k = 0; k < OUT; k++) obB[k] = accB[k];
}

extern "C" void kernel_launch(void* const* d_in, const int* in_sizes, int n_in,
                              void* d_out, int out_size, void* d_ws, size_t ws_size,
                              hipStream_t stream) {
    const float* f0    = (const float*)d_in[0];
    const float* f1    = (const float*)d_in[1];
    const float* f2    = (const float*)d_in[2];
    const float* f3    = (const float*)d_in[3];
    const float* boxes = (const float*)d_in[4];
    float* out = (float*)d_out;

    int N = in_sizes[0] / (CCH * 256 * 256);
    int M = in_sizes[4] / 4;
    int R = M / N;

    size_t nshorts = (size_t)N * CCH * (65536 + 16384 + 4096 + 1024);
    if (ws_size >= nshorts * sizeof(unsigned short)) {
        unsigned short* t0 = (unsigned short*)d_ws;
        unsigned short* t1 = t0 + (size_t)N * CCH * 65536;
        unsigned short* t2 = t1 + (size_t)N * CCH * 16384;
        unsigned short* t3 = t2 + (size_t)N * CCH * 4096;
        int tblocks = (4096 + 1024 + 256 + 64) * N;   // 5440*N
        transpose_all<<<tblocks, 256, 0, stream>>>(f0, f1, f2, f3, t0, t1, t2, t3, N);
        roi_pool_cl2<<<M * OUT, 128, 0, stream>>>(t0, t1, t2, t3, boxes, out, M, R);
    } else {
        int total = M * CCH * OUT * OUT;
        roi_pool_naive<<<(total + 255) / 256, 256, 0, stream>>>(f0, f1, f2, f3, boxes, out, M, R);
    }
}

// Round 4
// 296.147 us; speedup vs baseline: 1.3051x; 1.0014x over previous
//
#include <hip/hip_runtime.h>

#define OUT 7
#define CCH 256

__device__ __forceinline__ unsigned short f2bf(float f) {
    union { float f; unsigned int u; } v; v.f = f;
    unsigned int r = (v.u + 0x7FFFu + ((v.u >> 16) & 1u)) >> 16;   // RNE
    return (unsigned short)r;
}
__device__ __forceinline__ float bf2f_lo(unsigned int u) {
    union { unsigned int u; float f; } v; v.u = u << 16;
    return v.f;
}
__device__ __forceinline__ float bf2f_hi(unsigned int u) {
    union { unsigned int u; float f; } v; v.u = u & 0xFFFF0000u;
    return v.f;
}

// ---------------- fallback: one thread per output elem (no ws needed) ------
__global__ __launch_bounds__(256) void roi_pool_naive(
    const float* __restrict__ f0, const float* __restrict__ f1,
    const float* __restrict__ f2, const float* __restrict__ f3,
    const float* __restrict__ boxes, float* __restrict__ out,
    int M, int R)
{
    int idx = blockIdx.x * blockDim.x + threadIdx.x;
    int total = M * CCH * OUT * OUT;
    if (idx >= total) return;
    int pw = idx % OUT;
    int ph = (idx / OUT) % OUT;
    int c  = (idx / (OUT * OUT)) % CCH;
    int m  = idx / (OUT * OUT * CCH);
    int n  = m / R;
    const float bx1 = boxes[m * 4 + 0], by1 = boxes[m * 4 + 1];
    const float bx2 = boxes[m * 4 + 2], by2 = boxes[m * 4 + 3];
    float sz  = sqrtf(fmaxf((bx2 - bx1) * (by2 - by1), 0.0f));
    int lvl = (int)floorf(4.0f + log2f(sz / 224.0f + 1e-8f));
    lvl = min(max(lvl, 2), 5) - 2;
    const float* feat; int H, W; float scale;
    switch (lvl) {
        case 0:  feat = f0; H = 256; W = 256; scale = 0.25f;    break;
        case 1:  feat = f1; H = 128; W = 128; scale = 0.125f;   break;
        case 2:  feat = f2; H = 64;  W = 64;  scale = 0.0625f;  break;
        default: feat = f3; H = 32;  W = 32;  scale = 0.03125f; break;
    }
    const float* fp = feat + (size_t)(n * CCH + c) * (size_t)(H * W);
    float x1 = bx1 * scale - 0.5f, y1 = by1 * scale - 0.5f;
    float x2 = bx2 * scale - 0.5f, y2 = by2 * scale - 0.5f;
    float bw = (x2 - x1) * (1.0f / OUT), bh = (y2 - y1) * (1.0f / OUT);
    float acc = 0.0f;
    #pragma unroll
    for (int iy = 0; iy < 2; iy++) {
        float ys = y1 + ((float)ph + ((float)iy + 0.5f) * 0.5f) * bh;
        bool vy = (ys >= -1.0f) && (ys <= (float)H);
        float y = fminf(fmaxf(ys, 0.0f), (float)(H - 1));
        int y0 = (int)y;
        int y1i = min(y0 + 1, H - 1);
        float ly = y - (float)y0, hy = 1.0f - ly;
        #pragma unroll
        for (int ix = 0; ix < 2; ix++) {
            float xs = x1 + ((float)pw + ((float)ix + 0.5f) * 0.5f) * bw;
            bool vx = (xs >= -1.0f) && (xs <= (float)W);
            float x = fminf(fmaxf(xs, 0.0f), (float)(W - 1));
            int x0 = (int)x;
            int x1ii = min(x0 + 1, W - 1);
            float lx = x - (float)x0, hx = 1.0f - lx;
            if (vy && vx) {
                acc += hy * hx * fp[y0 * W + x0]  + hy * lx * fp[y0 * W + x1ii]
                     + ly * hx * fp[y1i * W + x0] + ly * lx * fp[y1i * W + x1ii];
            }
        }
    }
    out[idx] = acc * 0.25f;
}

// ---- fused NCHW fp32 -> NHWC bf16 transpose v3 -----------------------------
// One block = 64 hw x ALL 256 channels -> output is a CONTIGUOUS 32 KB region
// of NHWC (full-line 16 B/lane uint4 stores). bf16 stored in LDS as hw-pairs
// (uint), rotation-swizzled so both ds_write_b64 (load phase) and ds_read_b32
// (store phase) are conflict-free. LDS 32 KB/block -> 5 blocks/CU.
__global__ __launch_bounds__(256) void transpose_all(
    const float* __restrict__ f0, const float* __restrict__ f1,
    const float* __restrict__ f2, const float* __restrict__ f3,
    unsigned short* __restrict__ o0, unsigned short* __restrict__ o1,
    unsigned short* __restrict__ o2, unsigned short* __restrict__ o3,
    int N)
{
    __shared__ unsigned int lds[CCH][32];   // [c][swizzled hw-pair]; 32 KB

    int rem = blockIdx.x;
    const int nb0 = 1024 * N;   // 64-hw tiles per level (x N images)
    const int nb1 = 256 * N;
    const int nb2 = 64 * N;
    const float* in; unsigned short* op; int HW, lshift;
    if (rem < nb0)        { in = f0; op = o0; HW = 65536; lshift = 10; }
    else { rem -= nb0;
      if (rem < nb1)      { in = f1; op = o1; HW = 16384; lshift = 8;  }
      else { rem -= nb1;
        if (rem < nb2)    { in = f2; op = o2; HW = 4096;  lshift = 6;  }
        else { rem -= nb2;  in = f3; op = o3; HW = 1024;  lshift = 4;  }
      }
    }
    int hw0 = (rem & ((1 << lshift) - 1)) << 6;
    int n   = rem >> lshift;

    int t  = threadIdx.x;
    int tx = t & 15;     // hw:  4 consecutive elems at 4*tx
    int ty = t >> 4;     // c:   ty + 16*j

    const float4* in4 = (const float4*)(in + (size_t)n * CCH * HW);
    #pragma unroll
    for (int j = 0; j < 16; j++) {
        int c = ty + 16 * j;
        float4 v = in4[((size_t)c * HW + (size_t)hw0) / 4 + tx];
        unsigned int u0 = (unsigned int)f2bf(v.x) | ((unsigned int)f2bf(v.y) << 16); // hwpair 2tx
        unsigned int u1 = (unsigned int)f2bf(v.z) | ((unsigned int)f2bf(v.w) << 16); // hwpair 2tx+1
        int e   = 2 * (c >> 3) + 8 * (c & 3);          // even rotation
        int col = (2 * tx + e) & 31;                   // even -> 8B aligned pair
        *(uint2*)(&lds[c][col]) = make_uint2(u0, u1);
    }
    __syncthreads();

    int txc  = t & 31;   // channel block: 8*txc .. 8*txc+7
    int row8 = t >> 5;   // hw row within pass
    unsigned short* ob = op + (size_t)n * HW * CCH;
    #pragma unroll
    for (int p = 0; p < 8; p++) {
        int hwl = 8 * p + row8;       // 0..63
        int hwp = hwl >> 1;
        int sel = hwl & 1;
        unsigned int w[4];
        #pragma unroll
        for (int kk = 0; kk < 4; kk++) {
            int ca = 8 * txc + 2 * kk;        // even channel
            int cb = ca + 1;                  // odd channel
            unsigned int ua = lds[ca][(hwp + 2 * txc + 8 * ((2 * kk) & 3)) & 31];
            unsigned int ub = lds[cb][(hwp + 2 * txc + 8 * ((2 * kk + 1) & 3)) & 31];
            unsigned int ha = sel ? (ua >> 16)          : (ua & 0xFFFFu);
            unsigned int hb = sel ? (ub & 0xFFFF0000u)  : (ub << 16);
            w[kk] = ha | hb;                  // channels ca (lo), cb (hi)
        }
        uint4 vv; vv.x = w[0]; vv.y = w[1]; vv.z = w[2]; vv.w = w[3];
        ((uint4*)(ob + (size_t)(hw0 + hwl) * CCH))[txc] = vv;
    }
}

// ---- main: one block per (box, ph); 128 threads; lane = 2 channels (uint) --
// (unchanged from round 3 — single-variable discipline)
__global__ __launch_bounds__(128) void roi_pool_cl2(
    const unsigned short* __restrict__ t0, const unsigned short* __restrict__ t1,
    const unsigned short* __restrict__ t2, const unsigned short* __restrict__ t3,
    const float* __restrict__ boxes, float* __restrict__ out, int M, int R)
{
    int bx = blockIdx.x;
    int m, ph;
    if ((M & 7) == 0) {
        int q = bx / 56, rem = bx - q * 56;
        ph = rem >> 3;
        m  = q * 8 + (rem & 7);
    } else {
        m = bx / OUT; ph = bx % OUT;
    }
    int t = threadIdx.x;          // channel-pair index: channels 2t, 2t+1
    int n = m / R;

    const float bx1 = boxes[m * 4 + 0], by1 = boxes[m * 4 + 1];
    const float bx2 = boxes[m * 4 + 2], by2 = boxes[m * 4 + 3];
    float sz  = sqrtf(fmaxf((bx2 - bx1) * (by2 - by1), 0.0f));
    int lvl = (int)floorf(4.0f + log2f(sz / 224.0f + 1e-8f));
    lvl = min(max(lvl, 2), 5) - 2;

    const unsigned short* feat; int H, W; float scale;
    switch (lvl) {
        case 0:  feat = t0; H = 256; W = 256; scale = 0.25f;    break;
        case 1:  feat = t1; H = 128; W = 128; scale = 0.125f;   break;
        case 2:  feat = t2; H = 64;  W = 64;  scale = 0.0625f;  break;
        default: feat = t3; H = 32;  W = 32;  scale = 0.03125f; break;
    }
    const unsigned short* fb = feat + (size_t)n * H * W * CCH;

    float x1 = bx1 * scale - 0.5f, y1 = by1 * scale - 0.5f;
    float x2 = bx2 * scale - 0.5f, y2 = by2 * scale - 0.5f;
    float bw = (x2 - x1) * (1.0f / OUT), bh = (y2 - y1) * (1.0f / OUT);

    int   r0[2], r1[2];
    float lyv[2], hyv[2];
    bool  vyv[2];
    #pragma unroll
    for (int iy = 0; iy < 2; iy++) {
        float ys = y1 + ((float)ph + ((float)iy + 0.5f) * 0.5f) * bh;
        vyv[iy] = (ys >= -1.0f) && (ys <= (float)H);
        float y = fminf(fmaxf(ys, 0.0f), (float)(H - 1));
        int y0 = (int)y;
        int y1i = min(y0 + 1, H - 1);
        lyv[iy] = y - (float)y0;
        hyv[iy] = 1.0f - lyv[iy];
        r0[iy] = y0 * W * CCH;
        r1[iy] = y1i * W * CCH;
    }

    float accA[OUT];   // channel 2t
    float accB[OUT];   // channel 2t+1
    #pragma unroll
    for (int pw = 0; pw < OUT; pw++) {
        float aA = 0.0f, aB = 0.0f;
        #pragma unroll
        for (int ix = 0; ix < 2; ix++) {
            float xs = x1 + ((float)pw + ((float)ix + 0.5f) * 0.5f) * bw;
            bool vx = (xs >= -1.0f) && (xs <= (float)W);
            float x = fminf(fmaxf(xs, 0.0f), (float)(W - 1));
            int x0 = (int)x;
            int x1i = min(x0 + 1, W - 1);
            float lx = x - (float)x0;
            float hx = 1.0f - lx;
            int c0o = x0 * CCH;
            int c1o = x1i * CCH;
            #pragma unroll
            for (int iy = 0; iy < 2; iy++) {
                if (vyv[iy] && vx) {
                    const unsigned int* p00 = (const unsigned int*)(fb + __builtin_amdgcn_readfirstlane(r0[iy] + c0o));
                    const unsigned int* p01 = (const unsigned int*)(fb + __builtin_amdgcn_readfirstlane(r0[iy] + c1o));
                    const unsigned int* p10 = (const unsigned int*)(fb + __builtin_amdgcn_readfirstlane(r1[iy] + c0o));
                    const unsigned int* p11 = (const unsigned int*)(fb + __builtin_amdgcn_readfirstlane(r1[iy] + c1o));
                    unsigned int u00 = p00[t], u01 = p01[t];
                    unsigned int u10 = p10[t], u11 = p11[t];
                    float w00 = hyv[iy] * hx, w01 = hyv[iy] * lx;
                    float w10 = lyv[iy] * hx, w11 = lyv[iy] * lx;
                    aA += w00 * bf2f_lo(u00) + w01 * bf2f_lo(u01)
                        + w10 * bf2f_lo(u10) + w11 * bf2f_lo(u11);
                    aB += w00 * bf2f_hi(u00) + w01 * bf2f_hi(u01)
                        + w10 * bf2f_hi(u10) + w11 * bf2f_hi(u11);
                }
            }
        }
        accA[pw] = aA * 0.25f;
        accB[pw] = aB * 0.25f;
    }

    float* obA = out + (size_t)m * (CCH * OUT * OUT) + (size_t)(2 * t) * (OUT * OUT) + ph * OUT;
    float* obB = obA + (OUT * OUT);
    #pragma unroll
    for (int k = 0; k < OUT; k++) obA[k] = accA[k];
    #pragma unroll
    for (int k = 0; k < OUT; k++) obB[k] = accB[k];
}

extern "C" void kernel_launch(void* const* d_in, const int* in_sizes, int n_in,
                              void* d_out, int out_size, void* d_ws, size_t ws_size,
                              hipStream_t stream) {
    const float* f0    = (const float*)d_in[0];
    const float* f1    = (const float*)d_in[1];
    const float* f2    = (const float*)d_in[2];
    const float* f3    = (const float*)d_in[3];
    const float* boxes = (const float*)d_in[4];
    float* out = (float*)d_out;

    int N = in_sizes[0] / (CCH * 256 * 256);
    int M = in_sizes[4] / 4;
    int R = M / N;

    size_t nshorts = (size_t)N * CCH * (65536 + 16384 + 4096 + 1024);
    if (ws_size >= nshorts * sizeof(unsigned short)) {
        unsigned short* t0 = (unsigned short*)d_ws;
        unsigned short* t1 = t0 + (size_t)N * CCH * 65536;
        unsigned short* t2 = t1 + (size_t)N * CCH * 16384;
        unsigned short* t3 = t2 + (size_t)N * CCH * 4096;
        int tblocks = (1024 + 256 + 64 + 16) * N;   // 1360*N, 64-hw x 256-c tiles
        transpose_all<<<tblocks, 256, 0, stream>>>(f0, f1, f2, f3, t0, t1, t2, t3, N);
        roi_pool_cl2<<<M * OUT, 128, 0, stream>>>(t0, t1, t2, t3, boxes, out, M, R);
    } else {
        int total = M * CCH * OUT * OUT;
        roi_pool_naive<<<(total + 255) / 256, 256, 0, stream>>>(f0, f1, f2, f3, boxes, out, M, R);
    }
}

// Round 5
// 294.158 us; speedup vs baseline: 1.3139x; 1.0068x over previous
//
#include <hip/hip_runtime.h>

#define OUT 7
#define CCH 256

__device__ __forceinline__ unsigned short f2bf(float f) {
    union { float f; unsigned int u; } v; v.f = f;
    unsigned int r = (v.u + 0x7FFFu + ((v.u >> 16) & 1u)) >> 16;   // RNE
    return (unsigned short)r;
}
__device__ __forceinline__ float bf2f_lo(unsigned int u) {
    union { unsigned int u; float f; } v; v.u = u << 16;
    return v.f;
}
__device__ __forceinline__ float bf2f_hi(unsigned int u) {
    union { unsigned int u; float f; } v; v.u = u & 0xFFFF0000u;
    return v.f;
}

// ---------------- fallback: one thread per output elem (no ws needed) ------
__global__ __launch_bounds__(256) void roi_pool_naive(
    const float* __restrict__ f0, const float* __restrict__ f1,
    const float* __restrict__ f2, const float* __restrict__ f3,
    const float* __restrict__ boxes, float* __restrict__ out,
    int M, int R)
{
    int idx = blockIdx.x * blockDim.x + threadIdx.x;
    int total = M * CCH * OUT * OUT;
    if (idx >= total) return;
    int pw = idx % OUT;
    int ph = (idx / OUT) % OUT;
    int c  = (idx / (OUT * OUT)) % CCH;
    int m  = idx / (OUT * OUT * CCH);
    int n  = m / R;
    const float bx1 = boxes[m * 4 + 0], by1 = boxes[m * 4 + 1];
    const float bx2 = boxes[m * 4 + 2], by2 = boxes[m * 4 + 3];
    float sz  = sqrtf(fmaxf((bx2 - bx1) * (by2 - by1), 0.0f));
    int lvl = (int)floorf(4.0f + log2f(sz / 224.0f + 1e-8f));
    lvl = min(max(lvl, 2), 5) - 2;
    const float* feat; int H, W; float scale;
    switch (lvl) {
        case 0:  feat = f0; H = 256; W = 256; scale = 0.25f;    break;
        case 1:  feat = f1; H = 128; W = 128; scale = 0.125f;   break;
        case 2:  feat = f2; H = 64;  W = 64;  scale = 0.0625f;  break;
        default: feat = f3; H = 32;  W = 32;  scale = 0.03125f; break;
    }
    const float* fp = feat + (size_t)(n * CCH + c) * (size_t)(H * W);
    float x1 = bx1 * scale - 0.5f, y1 = by1 * scale - 0.5f;
    float x2 = bx2 * scale - 0.5f, y2 = by2 * scale - 0.5f;
    float bw = (x2 - x1) * (1.0f / OUT), bh = (y2 - y1) * (1.0f / OUT);
    float acc = 0.0f;
    #pragma unroll
    for (int iy = 0; iy < 2; iy++) {
        float ys = y1 + ((float)ph + ((float)iy + 0.5f) * 0.5f) * bh;
        bool vy = (ys >= -1.0f) && (ys <= (float)H);
        float y = fminf(fmaxf(ys, 0.0f), (float)(H - 1));
        int y0 = (int)y;
        int y1i = min(y0 + 1, H - 1);
        float ly = y - (float)y0, hy = 1.0f - ly;
        #pragma unroll
        for (int ix = 0; ix < 2; ix++) {
            float xs = x1 + ((float)pw + ((float)ix + 0.5f) * 0.5f) * bw;
            bool vx = (xs >= -1.0f) && (xs <= (float)W);
            float x = fminf(fmaxf(xs, 0.0f), (float)(W - 1));
            int x0 = (int)x;
            int x1ii = min(x0 + 1, W - 1);
            float lx = x - (float)x0, hx = 1.0f - lx;
            if (vy && vx) {
                acc += hy * hx * fp[y0 * W + x0]  + hy * lx * fp[y0 * W + x1ii]
                     + ly * hx * fp[y1i * W + x0] + ly * lx * fp[y1i * W + x1ii];
            }
        }
    }
    out[idx] = acc * 0.25f;
}

// ---- fused NCHW fp32 -> NHWC bf16 transpose v4 -----------------------------
// Tile = 256 hw x 64 c. KEY CHANGE vs v3: each global-read instruction is ONE
// channel's 256-float row = 1 KB CONTIGUOUS (was 4 x 256-B segments strided
// 256 KB -> DRAM row thrash, the suspected 2 TB/s cap). Loads batched 16-deep.
// LDS: bf16 hw-pairs, uint lds[64][128] (32 KB), rotation swizzle
// rot(c)=2c+4(c>>3): ds_write_b64 uniform (min), ds_read_b32 covers all 32
// banks (verified: {20j+4kk} ⊕ {hwp 0..3} = all banks; same-addr pairs
// broadcast). Writes: per hw row 128-B chunk = 2 full lines.
__global__ __launch_bounds__(256) void transpose_all(
    const float* __restrict__ f0, const float* __restrict__ f1,
    const float* __restrict__ f2, const float* __restrict__ f3,
    unsigned short* __restrict__ o0, unsigned short* __restrict__ o1,
    unsigned short* __restrict__ o2, unsigned short* __restrict__ o3,
    int N)
{
    __shared__ unsigned int lds[64][128];   // [c_local][swizzled hw-pair]; 32 KB

    int rem = blockIdx.x;
    const int nb0 = 1024 * N;   // 256 hw-tiles * 4 c-tiles * N
    const int nb1 = 256 * N;    // 64 * 4 * N
    const int nb2 = 64 * N;     // 16 * 4 * N
    const float* in; unsigned short* op; int HW, shift;
    if (rem < nb0)        { in = f0; op = o0; HW = 65536; shift = 8; }
    else { rem -= nb0;
      if (rem < nb1)      { in = f1; op = o1; HW = 16384; shift = 6; }
      else { rem -= nb1;
        if (rem < nb2)    { in = f2; op = o2; HW = 4096;  shift = 4; }
        else { rem -= nb2;  in = f3; op = o3; HW = 1024;  shift = 2; }
      }
    }
    int hw0 = (rem & ((1 << shift) - 1)) << 8;     // hw-tile * 256
    int c0  = ((rem >> shift) & 3) << 6;           // c-tile * 64
    int n   = rem >> (shift + 2);

    int t = threadIdx.x;
    int w = t >> 6;      // wave 0..3
    int l = t & 63;      // lane

    // ---- phase 1: 16 x 1-KB contiguous row loads, batched ----
    const float4* in4 = (const float4*)(in + ((size_t)n * CCH + c0) * HW);
    float4 v[16];
    #pragma unroll
    for (int i = 0; i < 16; i++) {
        int c = 16 * w + i;                                  // local channel
        v[i] = in4[((size_t)c * HW + hw0) / 4 + l];          // lane l: float4 #l of row
    }
    #pragma unroll
    for (int i = 0; i < 16; i++) {
        int c = 16 * w + i;
        unsigned int u0 = (unsigned int)f2bf(v[i].x) | ((unsigned int)f2bf(v[i].y) << 16); // hw pair 2l
        unsigned int u1 = (unsigned int)f2bf(v[i].z) | ((unsigned int)f2bf(v[i].w) << 16); // hw pair 2l+1
        int rot = (2 * c + 4 * (c >> 3)) & 127;              // even rotation
        int col = (2 * l + rot) & 127;                       // even -> 8B aligned
        *(uint2*)(&lds[c][col]) = make_uint2(u0, u1);
    }
    __syncthreads();

    // ---- phase 2: assemble NHWC rows, 128-B (2 full lines) per hw row ----
    int tl = t & 7;          // channel-octet: channels 8*tl .. 8*tl+7 (local)
    int tr = t >> 3;         // 0..31 hw-row selector
    unsigned short* ob = op + (size_t)n * HW * CCH + c0;
    #pragma unroll
    for (int p = 0; p < 8; p++) {
        int hwl = p * 32 + tr;        // 0..255
        int hwp = hwl >> 1;
        int sel = hwl & 1;
        unsigned int wv[4];
        #pragma unroll
        for (int kk = 0; kk < 4; kk++) {
            int ca = 8 * tl + 2 * kk;          // even local channel
            int cb = ca + 1;                   // odd local channel
            int rota = (2 * ca + 4 * (ca >> 3)) & 127;
            int rotb = (2 * cb + 4 * (cb >> 3)) & 127;
            unsigned int ua = lds[ca][(hwp + rota) & 127];
            unsigned int ub = lds[cb][(hwp + rotb) & 127];
            unsigned int ha = sel ? (ua >> 16)         : (ua & 0xFFFFu);
            unsigned int hb = sel ? (ub & 0xFFFF0000u) : (ub << 16);
            wv[kk] = ha | hb;                  // channels ca (lo), cb (hi)
        }
        uint4 vv; vv.x = wv[0]; vv.y = wv[1]; vv.z = wv[2]; vv.w = wv[3];
        ((uint4*)(ob + (size_t)(hw0 + hwl) * CCH))[tl] = vv;
    }
}

// ---- main: one block per (box, ph); 128 threads; lane = 2 channels (uint) --
// (unchanged — single-variable discipline)
__global__ __launch_bounds__(128) void roi_pool_cl2(
    const unsigned short* __restrict__ t0, const unsigned short* __restrict__ t1,
    const unsigned short* __restrict__ t2, const unsigned short* __restrict__ t3,
    const float* __restrict__ boxes, float* __restrict__ out, int M, int R)
{
    int bx = blockIdx.x;
    int m, ph;
    if ((M & 7) == 0) {
        int q = bx / 56, rem = bx - q * 56;
        ph = rem >> 3;
        m  = q * 8 + (rem & 7);
    } else {
        m = bx / OUT; ph = bx % OUT;
    }
    int t = threadIdx.x;          // channel-pair index: channels 2t, 2t+1
    int n = m / R;

    const float bx1 = boxes[m * 4 + 0], by1 = boxes[m * 4 + 1];
    const float bx2 = boxes[m * 4 + 2], by2 = boxes[m * 4 + 3];
    float sz  = sqrtf(fmaxf((bx2 - bx1) * (by2 - by1), 0.0f));
    int lvl = (int)floorf(4.0f + log2f(sz / 224.0f + 1e-8f));
    lvl = min(max(lvl, 2), 5) - 2;

    const unsigned short* feat; int H, W; float scale;
    switch (lvl) {
        case 0:  feat = t0; H = 256; W = 256; scale = 0.25f;    break;
        case 1:  feat = t1; H = 128; W = 128; scale = 0.125f;   break;
        case 2:  feat = t2; H = 64;  W = 64;  scale = 0.0625f;  break;
        default: feat = t3; H = 32;  W = 32;  scale = 0.03125f; break;
    }
    const unsigned short* fb = feat + (size_t)n * H * W * CCH;

    float x1 = bx1 * scale - 0.5f, y1 = by1 * scale - 0.5f;
    float x2 = bx2 * scale - 0.5f, y2 = by2 * scale - 0.5f;
    float bw = (x2 - x1) * (1.0f / OUT), bh = (y2 - y1) * (1.0f / OUT);

    int   r0[2], r1[2];
    float lyv[2], hyv[2];
    bool  vyv[2];
    #pragma unroll
    for (int iy = 0; iy < 2; iy++) {
        float ys = y1 + ((float)ph + ((float)iy + 0.5f) * 0.5f) * bh;
        vyv[iy] = (ys >= -1.0f) && (ys <= (float)H);
        float y = fminf(fmaxf(ys, 0.0f), (float)(H - 1));
        int y0 = (int)y;
        int y1i = min(y0 + 1, H - 1);
        lyv[iy] = y - (float)y0;
        hyv[iy] = 1.0f - lyv[iy];
        r0[iy] = y0 * W * CCH;
        r1[iy] = y1i * W * CCH;
    }

    float accA[OUT];   // channel 2t
    float accB[OUT];   // channel 2t+1
    #pragma unroll
    for (int pw = 0; pw < OUT; pw++) {
        float aA = 0.0f, aB = 0.0f;
        #pragma unroll
        for (int ix = 0; ix < 2; ix++) {
            float xs = x1 + ((float)pw + ((float)ix + 0.5f) * 0.5f) * bw;
            bool vx = (xs >= -1.0f) && (xs <= (float)W);
            float x = fminf(fmaxf(xs, 0.0f), (float)(W - 1));
            int x0 = (int)x;
            int x1i = min(x0 + 1, W - 1);
            float lx = x - (float)x0;
            float hx = 1.0f - lx;
            int c0o = x0 * CCH;
            int c1o = x1i * CCH;
            #pragma unroll
            for (int iy = 0; iy < 2; iy++) {
                if (vyv[iy] && vx) {
                    const unsigned int* p00 = (const unsigned int*)(fb + __builtin_amdgcn_readfirstlane(r0[iy] + c0o));
                    const unsigned int* p01 = (const unsigned int*)(fb + __builtin_amdgcn_readfirstlane(r0[iy] + c1o));
                    const unsigned int* p10 = (const unsigned int*)(fb + __builtin_amdgcn_readfirstlane(r1[iy] + c0o));
                    const unsigned int* p11 = (const unsigned int*)(fb + __builtin_amdgcn_readfirstlane(r1[iy] + c1o));
                    unsigned int u00 = p00[t], u01 = p01[t];
                    unsigned int u10 = p10[t], u11 = p11[t];
                    float w00 = hyv[iy] * hx, w01 = hyv[iy] * lx;
                    float w10 = lyv[iy] * hx, w11 = lyv[iy] * lx;
                    aA += w00 * bf2f_lo(u00) + w01 * bf2f_lo(u01)
                        + w10 * bf2f_lo(u10) + w11 * bf2f_lo(u11);
                    aB += w00 * bf2f_hi(u00) + w01 * bf2f_hi(u01)
                        + w10 * bf2f_hi(u10) + w11 * bf2f_hi(u11);
                }
            }
        }
        accA[pw] = aA * 0.25f;
        accB[pw] = aB * 0.25f;
    }

    float* obA = out + (size_t)m * (CCH * OUT * OUT) + (size_t)(2 * t) * (OUT * OUT) + ph * OUT;
    float* obB = obA + (OUT * OUT);
    #pragma unroll
    for (int k = 0; k < OUT; k++) obA[k] = accA[k];
    #pragma unroll
    for (int k = 0; k < OUT; k++) obB[k] = accB[k];
}

extern "C" void kernel_launch(void* const* d_in, const int* in_sizes, int n_in,
                              void* d_out, int out_size, void* d_ws, size_t ws_size,
                              hipStream_t stream) {
    const float* f0    = (const float*)d_in[0];
    const float* f1    = (const float*)d_in[1];
    const float* f2    = (const float*)d_in[2];
    const float* f3    = (const float*)d_in[3];
    const float* boxes = (const float*)d_in[4];
    float* out = (float*)d_out;

    int N = in_sizes[0] / (CCH * 256 * 256);
    int M = in_sizes[4] / 4;
    int R = M / N;

    size_t nshorts = (size_t)N * CCH * (65536 + 16384 + 4096 + 1024);
    if (ws_size >= nshorts * sizeof(unsigned short)) {
        unsigned short* t0 = (unsigned short*)d_ws;
        unsigned short* t1 = t0 + (size_t)N * CCH * 65536;
        unsigned short* t2 = t1 + (size_t)N * CCH * 16384;
        unsigned short* t3 = t2 + (size_t)N * CCH * 4096;
        int tblocks = (1024 + 256 + 64 + 16) * N;   // 256hw x 64c tiles, 4 c-tiles/level
        transpose_all<<<tblocks, 256, 0, stream>>>(f0, f1, f2, f3, t0, t1, t2, t3, N);
        roi_pool_cl2<<<M * OUT, 128, 0, stream>>>(t0, t1, t2, t3, boxes, out, M, R);
    } else {
        int total = M * CCH * OUT * OUT;
        roi_pool_naive<<<(total + 255) / 256, 256, 0, stream>>>(f0, f1, f2, f3, boxes, out, M, R);
    }
}